// Round 3
// baseline (396.140 us; speedup 1.0000x reference)
//
#include <hip/hip_runtime.h>

typedef unsigned short u16;
typedef unsigned int u32;
typedef __bf16 bf16x8 __attribute__((ext_vector_type(8)));
typedef float f32x4 __attribute__((ext_vector_type(4)));
typedef u16 u16x8 __attribute__((ext_vector_type(8)));

__device__ __forceinline__ u16 f2bf(float f) {
    union { float f; u32 i; } v; v.f = f;
    u32 x = v.i;
    u32 r = (x + 0x7fffu + ((x >> 16) & 1u)) >> 16;
    return (u16)r;
}
__device__ __forceinline__ float bf2f(u16 u) {
    union { u32 i; float f; } v; v.i = ((u32)u) << 16; return v.f;
}

// async global->LDS, 16B per lane. LDS dest must be lane-linear per wave.
__device__ __forceinline__ void gld16(const void* g, void* l) {
    __builtin_amdgcn_global_load_lds(
        (const __attribute__((address_space(1))) void*)g,
        (__attribute__((address_space(3))) void*)l, 16, 0, 0);
}

// -------- weight transpose+convert: 4 matrices [512][512] fp32 -> bf16^T ---
__global__ __launch_bounds__(256) void transpose4(
    const float* __restrict__ s0, const float* __restrict__ s1,
    const float* __restrict__ s2, const float* __restrict__ s3,
    u16* __restrict__ d0, u16* __restrict__ d1,
    u16* __restrict__ d2, u16* __restrict__ d3)
{
    int bx = blockIdx.x;
    int mat = bx >> 8;          // 0..3
    int tile = bx & 255;        // 16x16 tiles of 32x32
    int tx = (tile & 15) * 32;
    int ty = (tile >> 4) * 32;
    const float* src = (mat == 0) ? s0 : (mat == 1) ? s1 : (mat == 2) ? s2 : s3;
    u16* dst = (mat == 0) ? d0 : (mat == 1) ? d1 : (mat == 2) ? d2 : d3;

    __shared__ u16 tl[32][33];
    int col = threadIdx.x & 31;
    int r8  = threadIdx.x >> 5;   // 0..7
    #pragma unroll
    for (int k = 0; k < 4; ++k) {
        int rr = r8 + k * 8;
        tl[rr][col] = f2bf(src[(ty + rr) * 512 + tx + col]);
    }
    __syncthreads();
    #pragma unroll
    for (int k = 0; k < 4; ++k) {
        int rr = r8 + k * 8;
        dst[(tx + rr) * 512 + ty + col] = tl[col][rr];
    }
}

// -------- LayerNorm over H=512: fp32 in -> bf16 out, one wave per row -----
__global__ __launch_bounds__(256) void ln_k(
    const float* __restrict__ x, const float* __restrict__ g,
    const float* __restrict__ b, u16* __restrict__ y, int rows)
{
    int gid = blockIdx.x * blockDim.x + threadIdx.x;
    int row = gid >> 6;
    int lane = gid & 63;
    if (row >= rows) return;

    const float* xr = x + (size_t)row * 512 + lane * 8;
    float4 a0 = *(const float4*)xr;
    float4 a1 = *(const float4*)(xr + 4);
    float f[8] = {a0.x, a0.y, a0.z, a0.w, a1.x, a1.y, a1.z, a1.w};
    float s = 0.f, s2 = 0.f;
    #pragma unroll
    for (int e = 0; e < 8; ++e) { s += f[e]; s2 += f[e] * f[e]; }
    #pragma unroll
    for (int o = 32; o > 0; o >>= 1) { s += __shfl_xor(s, o); s2 += __shfl_xor(s2, o); }
    const float inv = 1.0f / 512.0f;
    float mean = s * inv;
    float var  = s2 * inv - mean * mean;
    float rstd = rsqrtf(var + 1e-5f);

    float4 g0 = *(const float4*)(g + lane * 8);
    float4 g1 = *(const float4*)(g + lane * 8 + 4);
    float4 b0 = *(const float4*)(b + lane * 8);
    float4 b1 = *(const float4*)(b + lane * 8 + 4);
    float gg[8] = {g0.x, g0.y, g0.z, g0.w, g1.x, g1.y, g1.z, g1.w};
    float bb[8] = {b0.x, b0.y, b0.z, b0.w, b1.x, b1.y, b1.z, b1.w};
    u16x8 ov;
    #pragma unroll
    for (int e = 0; e < 8; ++e)
        ov[e] = f2bf((f[e] - mean) * rstd * gg[e] + bb[e]);
    *(u16x8*)(y + (size_t)row * 512 + lane * 8) = ov;
}

// -------- GEMM: C[M=32768,N=512] = A[M,512](bf16) @ Bt[512,512](bf16)^T ----
// 256x256 tile, BK=64, 8 waves (2Mx4N), 512 thr, 8-phase schedule
// (4 phases per K-tile x 2 K-tiles in the LDS dbuf), counted vmcnt(6),
// setprio around MFMA clusters, raw s_barrier (no vmcnt(0) drain in-loop).
//
// LDS (128 KiB): A [2 slot][8 g][256 r] 16B granules at u16 idx
//   ((s*8+g)*256+r)*8 ; B same at +32768. Granule-major layout makes
//   ds_read_b128 conflict-free (wave: byte = q*4096 + l16*16 -> all 32
//   banks busy every cycle, 8-cycle floor) AND keeps each K-half region
//   (g 0-3 / 4-7) contiguous (16 KiB) so lane-linear global_load_lds can
//   stage it directly (no XOR; rule-21 satisfied trivially).
//
// Phases per K-tile t (slot s=t&1), quadrant = (k-slice ks, m-half ih):
//   P1: read A(ih0,ks0)+B(ks0); stage (t+1).A_k1   -> MFMA 16
//   P2: read A(ih1,ks0);        stage (t+2).B_k0   -> MFMA 16
//   P3: read A(ih0,ks1)+B(ks1); stage (t+2).A_k0   -> MFMA 16
//   P4: read A(ih1,ks1);        stage (t+2).B_k1   -> MFMA 16
// Every phase issues exactly 2 loads (stage targets wrap &7; the wrapped
// tail stages rewrite identical data, audited race-free) -> vmcnt(6) at
// every phase guarantees (in-order retirement) regions staged >=3 phases
// ago have landed; all reads target regions staged >=5 phases ago
// (2-pair margin). Mid-barrier publishes the landed state to all waves.
// Region WAR is safe: a region's last ds_read completes (lgkmcnt before
// MFMA) before the trailing barrier of its phase; its re-stage is issued
// >=1 phase later.
// EPI 0: bf16 out = A@B + bias ; EPI 1: relu ; EPI 2: fp32 out + resid.
template <int EPI>
__global__ __launch_bounds__(512, 2) void gemm8(
    const u16* __restrict__ A, const u16* __restrict__ Bt,
    const float* __restrict__ bias, const float* __restrict__ resid,
    void* __restrict__ outv)
{
    constexpr int Kd = 512, Nd = 512;
    __shared__ __align__(16) u16 lds[65536];   // 128 KiB

    // XCD swizzle: XCD x gets contiguous swz range -> (m,n) pairs of one
    // m-tile stay on one XCD (grid 256 = 8 XCDs x 32).
    int bid = blockIdx.x;
    int bx = (bid & 7) * 32 + (bid >> 3);
    int m0 = (bx >> 1) * 256;
    int n0 = (bx & 1) * 256;

    int tid = threadIdx.x;
    int lane = tid & 63;
    int w = tid >> 6;
    int wm = w >> 2, wn = w & 3;     // 2 x 4 waves
    int l16 = lane & 15, quad = lane >> 4;

    // staging invariants: thread covers row sr, granule layers sg / sg+2
    int sr = tid & 255;
    int sg = tid >> 8;               // 0..1
    const u16* aS = A  + (size_t)(m0 + sr) * Kd + sg * 8;
    const u16* bS = Bt + (size_t)(n0 + sr) * Kd + sg * 8;
    int dA = sg * 2048 + sr * 8;             // + s*16384 + h*8192 (+4096 g+2)
    int dB = 32768 + sg * 2048 + sr * 8;

    // ds_read invariants
    int aRd = quad * 2048 + (wm * 128 + l16) * 8;
    int bRd = 32768 + quad * 2048 + (wn * 64 + l16) * 8;

    f32x4 acc[8][4] = {};
    bf16x8 bfr[2][4];

#define STAGE_A(tt, h) { int s_ = (tt) & 1; const u16* p_ = aS + (tt) * 64 + (h) * 32; \
    gld16(p_,      &lds[s_ * 16384 + (h) * 8192 + dA]); \
    gld16(p_ + 16, &lds[s_ * 16384 + (h) * 8192 + dA + 4096]); }
#define STAGE_B(tt, h) { int s_ = (tt) & 1; const u16* p_ = bS + (tt) * 64 + (h) * 32; \
    gld16(p_,      &lds[s_ * 16384 + (h) * 8192 + dB]); \
    gld16(p_ + 16, &lds[s_ * 16384 + (h) * 8192 + dB + 4096]); }

#define PH(ks, ih, LOADB, ...) { \
    int fb_ = s * 16384 + (ks) * 8192; \
    bf16x8 af[4]; \
    _Pragma("unroll") \
    for (int ii = 0; ii < 4; ++ii) \
        af[ii] = *(const bf16x8*)&lds[fb_ + aRd + (ih) * 512 + ii * 128]; \
    if (LOADB) { \
        _Pragma("unroll") \
        for (int j = 0; j < 4; ++j) \
            bfr[ks][j] = *(const bf16x8*)&lds[fb_ + bRd + j * 128]; \
    } \
    __VA_ARGS__; \
    asm volatile("s_waitcnt vmcnt(6)" ::: "memory"); \
    __builtin_amdgcn_s_barrier(); \
    __builtin_amdgcn_s_setprio(1); \
    _Pragma("unroll") \
    for (int ii = 0; ii < 4; ++ii) { \
        _Pragma("unroll") \
        for (int j = 0; j < 4; ++j) \
            acc[(ih) * 4 + ii][j] = __builtin_amdgcn_mfma_f32_16x16x32_bf16( \
                af[ii], bfr[ks][j], acc[(ih) * 4 + ii][j], 0, 0, 0); \
    } \
    __builtin_amdgcn_s_setprio(0); \
    __builtin_amdgcn_sched_barrier(0); \
    __builtin_amdgcn_s_barrier(); \
}

    // prologue: tile0 fully + tile1 {B_k0, A_k0, B_k1}; tile1.A_k1 at t0.P1
    STAGE_B(0, 0); STAGE_A(0, 0); STAGE_B(0, 1); STAGE_A(0, 1);
    STAGE_B(1, 0); STAGE_A(1, 0); STAGE_B(1, 1);
    asm volatile("s_waitcnt vmcnt(6)" ::: "memory");   // tile0 landed
    __builtin_amdgcn_s_barrier();

    for (int t = 0; t < 8; ++t) {
        int s = t & 1;
        PH(0, 0, 1, STAGE_A((t + 1) & 7, 1));
        PH(0, 1, 0, STAGE_B((t + 2) & 7, 0));
        PH(1, 0, 1, STAGE_A((t + 2) & 7, 0));
        PH(1, 1, 0, STAGE_B((t + 2) & 7, 1));
    }
#undef PH
#undef STAGE_A
#undef STAGE_B

    // drain in-flight LDS-DMA before exiting (LDS may be reused next block)
    asm volatile("s_waitcnt vmcnt(0)" ::: "memory");
    __builtin_amdgcn_s_barrier();

    #pragma unroll
    for (int j = 0; j < 4; ++j) {
        int col = n0 + wn * 64 + j * 16 + l16;
        float bv = bias[col];
        #pragma unroll
        for (int i = 0; i < 8; ++i) {
            #pragma unroll
            for (int r = 0; r < 4; ++r) {
                int row = m0 + wm * 128 + i * 16 + quad * 4 + r;
                size_t off = (size_t)row * Nd + col;
                float v = acc[i][j][r] + bv;
                if (EPI == 0) {
                    ((u16*)outv)[off] = f2bf(v);
                } else if (EPI == 1) {
                    ((u16*)outv)[off] = f2bf(fmaxf(v, 0.f));
                } else {
                    ((float*)outv)[off] = v + resid[off];
                }
            }
        }
    }
}

// -------- minGRU scan (chunked linear recurrence) --------------------------
// h_t = c_t*h_{t-1} + v_t ; c = sigmoid(-k), v = sigmoid(k)*g(hp), h_0 = 0.5
// Chunk length 32 (256 chunks/seq) -> 8192 waves at scanA/scanC = full
// occupancy. Chunk-state scan is 3-level: compose-16 / scan-16 / replay-16.
__device__ __forceinline__ void gate_cv(u16 kraw, u16 hraw, float& c, float& v) {
    float kk = bf2f(kraw);
    float hh = bf2f(hraw);
    float z = 1.f / (1.f + __expf(-kk));   // sigmoid(k)
    c = 1.f / (1.f + __expf(kk));          // sigmoid(-k)
    float gg = (hh >= 0.f) ? (hh + 0.5f) : 1.f / (1.f + __expf(-hh));
    v = z * gg;
}

// Pass A: per-chunk (C, V) composition over chunk length 32.
__global__ __launch_bounds__(256) void scanA(
    const u16* __restrict__ kb, const u16* __restrict__ hp,
    float* __restrict__ chC, float* __restrict__ chV)
{
    int gid = blockIdx.x * 256 + threadIdx.x;   // 524288 threads
    int h = gid & 511;
    int rest = gid >> 9;
    int b = rest & 3;
    int ch = rest >> 2;             // 0..255
    size_t base = ((size_t)(b * 8192 + ch * 32)) * 512 + h;
    float C = 1.f, V = 0.f;
    #pragma unroll 8
    for (int t = 0; t < 32; ++t) {
        float c, v;
        gate_cv(kb[base + (size_t)t * 512], hp[base + (size_t)t * 512], c, v);
        C *= c;
        V = fmaf(c, V, v);
    }
    int s = b * 512 + h;
    chC[ch * 2048 + s] = C;
    chV[ch * 2048 + s] = V;
}

// Pass B1: compose 16 chunks -> superchunk state (16 superchunks/seq).
__global__ __launch_bounds__(256) void scanB1(
    const float* __restrict__ chC, const float* __restrict__ chV,
    float* __restrict__ scC, float* __restrict__ scV)
{
    int gid = blockIdx.x * 256 + threadIdx.x;  // 32768 threads
    int s = gid & 2047;
    int sc = gid >> 11;    // 0..15
    float C = 1.f, V = 0.f;
    #pragma unroll 4
    for (int i = 0; i < 16; ++i) {
        int ch = sc * 16 + i;
        float c = chC[ch * 2048 + s];
        float v = chV[ch * 2048 + s];
        C *= c;
        V = fmaf(c, V, v);
    }
    scC[sc * 2048 + s] = C;
    scV[sc * 2048 + s] = V;
}

// Pass B2: serial scan over 16 superchunk states; write start h per sc.
__global__ __launch_bounds__(256) void scanB2(
    const float* __restrict__ scC, const float* __restrict__ scV,
    float* __restrict__ sst)
{
    int s = blockIdx.x * 256 + threadIdx.x;   // 0..2047
    float hcur = 0.5f;
    #pragma unroll
    for (int sc = 0; sc < 16; ++sc) {
        sst[sc * 2048 + s] = hcur;
        hcur = fmaf(scC[sc * 2048 + s], hcur, scV[sc * 2048 + s]);
    }
}

// Pass B3: replay 16 chunks inside each superchunk; write start h per chunk.
__global__ __launch_bounds__(256) void scanB3(
    const float* __restrict__ chC, const float* __restrict__ chV,
    const float* __restrict__ sst, float* __restrict__ hst)
{
    int gid = blockIdx.x * 256 + threadIdx.x;  // 32768 threads
    int s = gid & 2047;
    int sc = gid >> 11;
    float hcur = sst[sc * 2048 + s];
    #pragma unroll 4
    for (int i = 0; i < 16; ++i) {
        int ch = sc * 16 + i;
        hst[ch * 2048 + s] = hcur;
        hcur = fmaf(chC[ch * 2048 + s], hcur, chV[ch * 2048 + s]);
    }
}

// Pass C: replay chunk with known h_start; x2 = x + h (fp32 in, fp32 out).
__global__ __launch_bounds__(256) void scanC(
    const u16* __restrict__ kb, const u16* __restrict__ hp,
    const float* __restrict__ hst, const float* __restrict__ x,
    float* __restrict__ x2)
{
    int gid = blockIdx.x * 256 + threadIdx.x;   // 524288 threads
    int h = gid & 511;
    int rest = gid >> 9;
    int b = rest & 3;
    int ch = rest >> 2;
    size_t base = ((size_t)(b * 8192 + ch * 32)) * 512 + h;
    float hcur = hst[ch * 2048 + b * 512 + h];
    #pragma unroll 8
    for (int t = 0; t < 32; ++t) {
        float c, v;
        size_t off = base + (size_t)t * 512;
        gate_cv(kb[off], hp[off], c, v);
        hcur = fmaf(c, hcur, v);
        x2[off] = x[off] + hcur;
    }
}

// ---------------------------------------------------------------------------
// All I/O fp32 (per reference). Internals bf16 for MFMA.
// ws layout (unchanged footprint):
//   wt  @ 0      : 2 MiB   (4 transposed bf16 weights)
//   a   @ 3.5 MiB: 32 MiB  bf16 (LN1 out -> LN2 out)
//     scan temps alias a's region (a is dead between gemms and LN2):
//     chC @ 3.5M (2M) ; chV @ 5.5M (2M) ; hst @ 7.5M (2M)
//     scC @ 9.5M (128K) ; scV ; sst
//   kb  @ 35.5 M : 32 MiB  bf16 (k preact -> FFN hidden)
//   hp  @ 67.5 M : 32 MiB  bf16 (h~ preact)
// d_out (fp32, 64 MiB) holds x2 after scanC, then the final output
// (gemm2 reads resid[off] then writes out[off] from the same thread).
extern "C" void kernel_launch(void* const* d_in, const int* in_sizes, int n_in,
                              void* d_out, int out_size, void* d_ws, size_t ws_size,
                              hipStream_t stream)
{
    const float* x    = (const float*)d_in[0];
    const float* ln1g = (const float*)d_in[1];
    const float* ln1b = (const float*)d_in[2];
    const float* Wz   = (const float*)d_in[3];
    const float* bz   = (const float*)d_in[4];
    const float* Wh   = (const float*)d_in[5];
    const float* bh   = (const float*)d_in[6];
    const float* ln2g = (const float*)d_in[7];
    const float* ln2b = (const float*)d_in[8];
    const float* W1   = (const float*)d_in[9];
    const float* b1   = (const float*)d_in[10];
    const float* W2   = (const float*)d_in[11];
    const float* b2   = (const float*)d_in[12];
    float* out = (float*)d_out;

    char* ws = (char*)d_ws;
    constexpr size_t MB = 1024 * 1024;
    u16* Wzt = (u16*)(ws);
    u16* Wht = Wzt + 262144;
    u16* W1t = Wzt + 524288;
    u16* W2t = Wzt + 786432;
    u16* a  = (u16*)(ws + 3 * MB + 512 * 1024);
    u16* kb = (u16*)(ws + 35 * MB + 512 * 1024);
    u16* hp = (u16*)(ws + 67 * MB + 512 * 1024);
    // scan temps alias 'a' (dead in that interval)
    float* chC = (float*)(ws + 3 * MB + 512 * 1024);
    float* chV = chC + 524288;          // +2 MiB
    float* hst = chV + 524288;          // +2 MiB
    float* scC = hst + 524288;          // +2 MiB
    float* scV = scC + 32768;           // +128 KiB
    float* sst = scV + 32768;           // +128 KiB

    transpose4<<<1024, 256, 0, stream>>>(Wz, Wh, W1, W2, Wzt, Wht, W1t, W2t);
    // a = bf16(LN1(x))
    ln_k<<<8192, 256, 0, stream>>>(x, ln1g, ln1b, a, 32768);
    // kb = a @ Wz + bz ; hp = a @ Wh + bh  (bf16)
    gemm8<0><<<256, 512, 0, stream>>>(a, Wzt, bz, nullptr, kb);
    gemm8<0><<<256, 512, 0, stream>>>(a, Wht, bh, nullptr, hp);
    scanA<<<2048, 256, 0, stream>>>(kb, hp, chC, chV);
    scanB1<<<128, 256, 0, stream>>>(chC, chV, scC, scV);
    scanB2<<<8, 256, 0, stream>>>(scC, scV, sst);
    scanB3<<<128, 256, 0, stream>>>(chC, chV, sst, hst);
    // d_out = x + h  (fp32 residual stream)
    scanC<<<2048, 256, 0, stream>>>(kb, hp, hst, x, out);
    // a = bf16(LN2(d_out))
    ln_k<<<8192, 256, 0, stream>>>(out, ln2g, ln2b, a, 32768);
    // kb = relu(a @ W1 + b1)  (bf16 hidden)
    gemm8<1><<<256, 512, 0, stream>>>(a, W1t, b1, nullptr, kb);
    // d_out = kb @ W2 + b2 + d_out  (fp32)
    gemm8<2><<<256, 512, 0, stream>>>(kb, W2t, b2, out, out);
}